// Round 4
// baseline (171.277 us; speedup 1.0000x reference)
//
#include <hip/hip_runtime.h>

#define NPTS 320
#define NCHUNK 8
#define PIX_PER_BLOCK 64
#define D0 2.0f
#define DSTEP (4.0f / 319.0f)
#define HALFV (765.0f / 512.0f)  // (3/256)*255*0.5
#define DENSITY_C 0.1f

// 8-byte vector load with only 4-byte guaranteed alignment (x0 is arbitrary).
typedef float f2a __attribute__((ext_vector_type(2), aligned(4)));

// ---------------------------------------------------------------------------
// Kernel 1: ray-march. Block = 512 threads = 8 waves. lane (0..63) = pixel,
// wave = 1/8 of that ray's ACTIVE sample interval (even work split — fixed
// depth-chunking left waves idle on clipped chunks). Fast interior path uses
// paired 8B x-loads (4 vmem insts/sample) and a regrouped compositing
// recurrence (t == 0.9 const) so groups of 4 samples are fully independent.
// ---------------------------------------------------------------------------
__global__ __launch_bounds__(512, 8)
void render_kernel(const float* __restrict__ vol,
                   const float* __restrict__ R,
                   const float* __restrict__ T,
                   float* __restrict__ raw,
                   float* __restrict__ bsum,
                   float* __restrict__ bsumsq,
                   float* __restrict__ bmin,
                   float* __restrict__ bmax) {
  const int lane  = threadIdx.x & 63;
  const int chunk = threadIdx.x >> 6;
  const int pixel = blockIdx.x * PIX_PER_BLOCK + lane;
  const int h = pixel >> 8;
  const int w = pixel & 255;

  // camera-plane coords / FOCAL(=2)
  const float xh = (w * (2.0f / 255.0f) - 1.0f) * 0.5f;
  const float yh = (h * (2.0f / 255.0f) - 1.0f) * 0.5f;

  const float R00 = R[0], R01 = R[1], R02 = R[2];
  const float R10 = R[3], R11 = R[4], R12 = R[5];
  const float R20 = R[6], R21 = R[7], R22 = R[8];
  const float T0 = T[0], T1 = T[1], T2 = T[2];

  // pw = R * (pcam - T); pcam = (xh*d, yh*d, d) -> voxel coords LINEAR in d.
  const float S = 127.5f / HALFV;
  const float Cx = R00 * xh + R01 * yh + R02;
  const float Cy = R10 * xh + R11 * yh + R12;
  const float Cz = R20 * xh + R21 * yh + R22;
  const float Kx = -(R00 * T0 + R01 * T1 + R02 * T2);
  const float Ky = -(R10 * T0 + R11 * T1 + R12 * T2);
  const float Kz = -(R20 * T0 + R21 * T1 + R22 * T2);
  const float ax = Cx * S, bx = Kx * S + 127.5f;
  const float ay = Cy * S, by = Ky * S + 127.5f;
  const float az = Cz * S, bz = Kz * S + 127.5f;
  // ix(p) = ix0 + p*dix with d = D0 + p*DSTEP
  const float ix0 = ax * D0 + bx, dix = ax * DSTEP;
  const float iy0 = ay * D0 + by, diy = ay * DSTEP;
  const float iz0 = az * D0 + bz, diz = az * DSTEP;

  // --- slab intervals in p-space -------------------------------------------
  float plo_in = -1e9f, phi_in = 1e9f, plo_out = -1e9f, phi_out = 1e9f;
  auto slab = [](float a, float b, float L, float H, float& lo, float& hi) {
    if (fabsf(a) < 1e-5f) {           // drift over 320 steps < 0.0032 < margin
      if (b < L || b > H) { lo = 1e9f; hi = -1e9f; }
    } else {
      const float p1 = (L - b) / a, p2 = (H - b) / a;
      lo = fmaxf(lo, fminf(p1, p2));
      hi = fminf(hi, fmaxf(p1, p2));
    }
  };
  slab(dix, ix0, 0.01f, 254.99f, plo_in, phi_in);
  slab(diy, iy0, 0.01f, 254.99f, plo_in, phi_in);
  slab(diz, iz0, 0.01f, 254.99f, plo_in, phi_in);
  slab(dix, ix0, -1.01f, 256.01f, plo_out, phi_out);
  slab(diy, iy0, -1.01f, 256.01f, plo_out, phi_out);
  slab(diz, iz0, -1.01f, 256.01f, plo_out, phi_out);

  const int i_in_lo  = (int)ceilf(fminf(fmaxf(plo_in, 0.0f), 320.0f));
  const int i_in_hi  = (int)floorf(fminf(fmaxf(phi_in, -1.0f), 319.0f)) + 1;
  const int i_out_lo = (int)ceilf(fminf(fmaxf(plo_out, 0.0f), 320.0f));
  const int i_out_hi = (int)floorf(fminf(fmaxf(phi_out, -1.0f), 319.0f)) + 1;

  // even split of the ray's active interval across the 8 waves
  const int rlo = max(0, i_out_lo);
  const int L   = max(0, min(NPTS, i_out_hi) - rlo);
  const int lo_o = rlo + ((chunk * L) >> 3);
  const int hi_o = rlo + (((chunk + 1) * L) >> 3);

  float acc = 0.0f;   // segment-local composited rgb
  float Tac = 1.0f;   // segment-local transmittance

  // exact (clamped + masked) sample — identical math to the round-1 kernel
  auto masked_sample = [&](int p) {
    const float pf = (float)p;
    const float ix = fmaf(pf, dix, ix0);
    const float iy = fmaf(pf, diy, iy0);
    const float iz = fmaf(pf, diz, iz0);
    if (ix > -1.0f && ix < 256.0f && iy > -1.0f && iy < 256.0f &&
        iz > -1.0f && iz < 256.0f) {
      const float xf = floorf(ix), yf = floorf(iy), zf = floorf(iz);
      const float fx = ix - xf, fy = iy - yf, fz = iz - zf;
      const int x0 = (int)xf, y0 = (int)yf, z0 = (int)zf;
      const float wx0 = (x0 >= 0)   ? 1.0f - fx : 0.0f;
      const float wx1 = (x0 <= 254) ? fx        : 0.0f;
      const float wy0 = (y0 >= 0)   ? 1.0f - fy : 0.0f;
      const float wy1 = (y0 <= 254) ? fy        : 0.0f;
      const float wz0 = (z0 >= 0)   ? 1.0f - fz : 0.0f;
      const float wz1 = (z0 <= 254) ? fz        : 0.0f;
      const int xc0 = max(x0, 0),     xc1 = min(x0 + 1, 255);
      const int yc0 = max(y0, 0),     yc1 = min(y0 + 1, 255);
      const int zc0 = max(z0, 0),     zc1 = min(z0 + 1, 255);
      const int b00 = (zc0 * 256 + yc0) * 256;
      const int b01 = (zc0 * 256 + yc1) * 256;
      const int b10 = (zc1 * 256 + yc0) * 256;
      const int b11 = (zc1 * 256 + yc1) * 256;
      const float v000 = vol[b00 + xc0], v001 = vol[b00 + xc1];
      const float v010 = vol[b01 + xc0], v011 = vol[b01 + xc1];
      const float v100 = vol[b10 + xc0], v101 = vol[b10 + xc1];
      const float v110 = vol[b11 + xc0], v111 = vol[b11 + xc1];
      const float fs =
          wz0 * (wy0 * (wx0 * v000 + wx1 * v001) +
                 wy1 * (wx0 * v010 + wx1 * v011)) +
          wz1 * (wy0 * (wx0 * v100 + wx1 * v101) +
                 wy1 * (wx0 * v110 + wx1 * v111));
      const float wsum  = (wx0 + wx1) * (wy0 + wy1) * (wz0 + wz1);
      const float sigma = DENSITY_C * wsum;
      acc = fmaf(sigma * Tac, fs, acc);
      Tac *= (1.0f + 1e-10f - sigma);
    } else {
      Tac *= (1.0f + 1e-10f);
    }
  };

  // interior trilinear sample: 4 paired 8B loads, no clamps/masks
  auto fast_sample = [&](int p) -> float {
    const float pf = (float)p;
    const float ix = fmaf(pf, dix, ix0);
    const float iy = fmaf(pf, diy, iy0);
    const float iz = fmaf(pf, diz, iz0);
    const int x0 = (int)ix, y0 = (int)iy, z0 = (int)iz;  // >=0: trunc==floor
    const float fx = ix - (float)x0;
    const float fy = iy - (float)y0;
    const float fz = iz - (float)z0;
    const int base = (z0 << 16) + (y0 << 8) + x0;
    const f2a v00 = *(const f2a*)(vol + base);
    const f2a v01 = *(const f2a*)(vol + base + 256);
    const f2a v10 = *(const f2a*)(vol + base + 65536);
    const f2a v11 = *(const f2a*)(vol + base + 65792);
    const float c00 = fmaf(fx, v00.y - v00.x, v00.x);
    const float c01 = fmaf(fx, v01.y - v01.x, v01.x);
    const float c10 = fmaf(fx, v10.y - v10.x, v10.x);
    const float c11 = fmaf(fx, v11.y - v11.x, v11.x);
    const float c0  = fmaf(fy, c01 - c00, c00);
    const float c1  = fmaf(fy, c11 - c10, c10);
    return fmaf(fz, c1 - c0, c0);
  };

  // partition [lo_o, hi_o) into masked | fast | masked
  const int lo_f = min(max(lo_o, i_in_lo), hi_o);
  const int hi_f = min(max(lo_f, i_in_hi), hi_o);

  for (int p = lo_o; p < lo_f; ++p) masked_sample(p);

  int p = lo_f;
#pragma unroll 1
  for (; p + 4 <= hi_f; p += 4) {
    const float fs0 = fast_sample(p);
    const float fs1 = fast_sample(p + 1);
    const float fs2 = fast_sample(p + 2);
    const float fs3 = fast_sample(p + 3);
    const float g = fmaf(0.729f, fs3,
                    fmaf(0.81f,  fs2,
                    fmaf(0.9f,   fs1, fs0)));
    acc = fmaf(Tac * DENSITY_C, g, acc);
    Tac *= 0.6561f;   // 0.9^4
  }
  for (; p < hi_f; ++p) {
    const float fs = fast_sample(p);
    acc = fmaf(Tac * DENSITY_C, fs, acc);
    Tac *= (1.0f - DENSITY_C);
  }

  for (p = hi_f; p < hi_o; ++p) masked_sample(p);

  __shared__ float lrgb[NCHUNK][PIX_PER_BLOCK];
  __shared__ float lT[NCHUNK][PIX_PER_BLOCK];
  lrgb[chunk][lane] = acc;
  lT[chunk][lane]   = Tac;
  __syncthreads();

  if (threadIdx.x < 64) {
    float a = 0.0f, Tp = 1.0f;
#pragma unroll
    for (int c = 0; c < NCHUNK; ++c) {
      a  = fmaf(Tp, lrgb[c][lane], a);
      Tp *= lT[c][lane];
    }
    raw[pixel] = a;

    float s = a, q = a * a, mn = a, mx = a;
#pragma unroll
    for (int off = 32; off > 0; off >>= 1) {
      s += __shfl_down(s, off, 64);
      q += __shfl_down(q, off, 64);
      mn = fminf(mn, __shfl_down(mn, off, 64));
      mx = fmaxf(mx, __shfl_down(mx, off, 64));
    }
    if (lane == 0) {
      bsum[blockIdx.x]   = s;
      bsumsq[blockIdx.x] = q;
      bmin[blockIdx.x]   = mn;
      bmax[blockIdx.x]   = mx;
    }
  }
}

// ---------------------------------------------------------------------------
// Kernel 2: fused stats + normalize + transpose. 256 blocks x 256 threads;
// stats via per-wave double shuffle reduction (4 waves) + tiny LDS combine.
// ---------------------------------------------------------------------------
__global__ __launch_bounds__(256)
void finalize_kernel(const float* __restrict__ raw,
                     const float* __restrict__ bsum,
                     const float* __restrict__ bsumsq,
                     const float* __restrict__ bmin,
                     const float* __restrict__ bmax,
                     float* __restrict__ out) {
  __shared__ double wS[4], wQ[4];
  __shared__ float wMn[4], wMx[4];
  const int t = threadIdx.x;
  const int lane = t & 63, wv = t >> 6;

  double s = 0.0, q = 0.0;
  float mn = 3.4e38f, mx = -3.4e38f;
#pragma unroll
  for (int i = 0; i < 4; ++i) {
    const int idx = t + i * 256;
    s += (double)bsum[idx];
    q += (double)bsumsq[idx];
    mn = fminf(mn, bmin[idx]);
    mx = fmaxf(mx, bmax[idx]);
  }
#pragma unroll
  for (int off = 32; off > 0; off >>= 1) {
    s += __shfl_down(s, off, 64);
    q += __shfl_down(q, off, 64);
    mn = fminf(mn, __shfl_down(mn, off, 64));
    mx = fmaxf(mx, __shfl_down(mx, off, 64));
  }
  if (lane == 0) { wS[wv] = s; wQ[wv] = q; wMn[wv] = mn; wMx[wv] = mx; }
  __syncthreads();
  const double sum   = wS[0] + wS[1] + wS[2] + wS[3];
  const double sumsq = wQ[0] + wQ[1] + wQ[2] + wQ[3];
  const float  gmn = fminf(fminf(wMn[0], wMn[1]), fminf(wMn[2], wMn[3]));
  const float  gmx = fmaxf(fmaxf(wMx[0], wMx[1]), fmaxf(wMx[2], wMx[3]));

  const double N = 65536.0;
  const double mean = sum / N;
  double var = (sumsq - sum * sum / N) / (N - 1.0);
  if (var < 0.0) var = 0.0;
  const float stdeps = (float)sqrt(var) + 1e-8f;
  const float inv_std = 1.0f / stdeps;
  const float fmean = (float)mean;
  const float smin = (gmn - fmean) * inv_std;
  const float smax = (gmx - fmean) * inv_std;
  const float inv_range = 1.0f / (smax - smin + 1e-8f);

  const int o = blockIdx.x * 256 + t;
  const int wq = o >> 8;    // output row (W index)
  const int hq = o & 255;   // output col (H index)
  const float sv = (raw[hq * 256 + wq] - fmean) * inv_std;
  out[o] = (sv - smin + 1e-8f) * inv_range;
}

extern "C" void kernel_launch(void* const* d_in, const int* in_sizes, int n_in,
                              void* d_out, int out_size, void* d_ws, size_t ws_size,
                              hipStream_t stream) {
  const float* vol = (const float*)d_in[0];  // (256,256,256) fp32
  const float* R   = (const float*)d_in[1];  // (1,3,3)
  const float* T   = (const float*)d_in[2];  // (1,3)
  float* out = (float*)d_out;                // 65536 fp32

  float* raw    = (float*)d_ws;              // 65536
  float* bsum   = raw + 65536;               // 1024
  float* bsumsq = bsum + 1024;               // 1024
  float* bmin   = bsumsq + 1024;             // 1024
  float* bmax   = bmin + 1024;               // 1024

  render_kernel<<<1024, 512, 0, stream>>>(vol, R, T, raw, bsum, bsumsq, bmin, bmax);
  finalize_kernel<<<256, 256, 0, stream>>>(raw, bsum, bsumsq, bmin, bmax, out);
}

// Round 5
// 125.465 us; speedup vs baseline: 1.3651x; 1.3651x over previous
//
#include <hip/hip_runtime.h>

#define NPTS 320
#define NCHUNK 8
#define PIX_PER_BLOCK 64
#define D0 2.0f
#define DSTEP (4.0f / 319.0f)
#define HALFV (765.0f / 512.0f)  // (3/256)*255*0.5
#define DENSITY_C 0.1f

// 8-byte vector load with only 4-byte guaranteed alignment (x0 is arbitrary).
typedef float f2a __attribute__((ext_vector_type(2), aligned(4)));

// ---------------------------------------------------------------------------
// Kernel 1: ray-march. Block = 512 threads = 8 waves over the SAME 64 rays.
// The block's active p-interval (wave-reduced UNION of per-ray slab
// intervals -> wave-uniform) is split evenly across the 8 waves; every lane
// walks the same p sequence (lockstep -> cache-line locality, round-4 lesson).
// Fast path (paired 8B loads, regrouped t=0.9 recurrence) runs only where
// ALL lanes are interior (wave-reduced INTERSECTION); elsewhere the exact
// masked path runs. Segmented compositing combined via LDS.
// ---------------------------------------------------------------------------
__global__ __launch_bounds__(512, 8)
void render_kernel(const float* __restrict__ vol,
                   const float* __restrict__ R,
                   const float* __restrict__ T,
                   float* __restrict__ raw,
                   float* __restrict__ bsum,
                   float* __restrict__ bsumsq,
                   float* __restrict__ bmin,
                   float* __restrict__ bmax) {
  const int lane  = threadIdx.x & 63;
  const int chunk = threadIdx.x >> 6;
  const int pixel = blockIdx.x * PIX_PER_BLOCK + lane;
  const int h = pixel >> 8;
  const int w = pixel & 255;

  // camera-plane coords / FOCAL(=2)
  const float xh = (w * (2.0f / 255.0f) - 1.0f) * 0.5f;
  const float yh = (h * (2.0f / 255.0f) - 1.0f) * 0.5f;

  const float R00 = R[0], R01 = R[1], R02 = R[2];
  const float R10 = R[3], R11 = R[4], R12 = R[5];
  const float R20 = R[6], R21 = R[7], R22 = R[8];
  const float T0 = T[0], T1 = T[1], T2 = T[2];

  // pw = R * (pcam - T); pcam = (xh*d, yh*d, d) -> voxel coords LINEAR in d.
  const float S = 127.5f / HALFV;
  const float Cx = R00 * xh + R01 * yh + R02;
  const float Cy = R10 * xh + R11 * yh + R12;
  const float Cz = R20 * xh + R21 * yh + R22;
  const float Kx = -(R00 * T0 + R01 * T1 + R02 * T2);
  const float Ky = -(R10 * T0 + R11 * T1 + R12 * T2);
  const float Kz = -(R20 * T0 + R21 * T1 + R22 * T2);
  const float ax = Cx * S, bx = Kx * S + 127.5f;
  const float ay = Cy * S, by = Ky * S + 127.5f;
  const float az = Cz * S, bz = Kz * S + 127.5f;
  // ix(p) = ix0 + p*dix with d = D0 + p*DSTEP
  const float ix0 = ax * D0 + bx, dix = ax * DSTEP;
  const float iy0 = ay * D0 + by, diy = ay * DSTEP;
  const float iz0 = az * D0 + bz, diz = az * DSTEP;

  // --- per-ray slab intervals in p-space -----------------------------------
  float plo_in = -1e9f, phi_in = 1e9f, plo_out = -1e9f, phi_out = 1e9f;
  auto slab = [](float a, float b, float L, float H, float& lo, float& hi) {
    if (fabsf(a) < 1e-5f) {           // drift over 320 steps < 0.0032 < margin
      if (b < L || b > H) { lo = 1e9f; hi = -1e9f; }
    } else {
      const float p1 = (L - b) / a, p2 = (H - b) / a;
      lo = fmaxf(lo, fminf(p1, p2));
      hi = fminf(hi, fmaxf(p1, p2));
    }
  };
  slab(dix, ix0, 0.01f, 254.99f, plo_in, phi_in);
  slab(diy, iy0, 0.01f, 254.99f, plo_in, phi_in);
  slab(diz, iz0, 0.01f, 254.99f, plo_in, phi_in);
  slab(dix, ix0, -1.01f, 256.01f, plo_out, phi_out);
  slab(diy, iy0, -1.01f, 256.01f, plo_out, phi_out);
  slab(diz, iz0, -1.01f, 256.01f, plo_out, phi_out);

  const int i_in_lo  = (int)ceilf(fminf(fmaxf(plo_in, 0.0f), 320.0f));
  const int i_in_hi  = (int)floorf(fminf(fmaxf(phi_in, -1.0f), 319.0f)) + 1;
  const int i_out_lo = (int)ceilf(fminf(fmaxf(plo_out, 0.0f), 320.0f));
  const int i_out_hi = (int)floorf(fminf(fmaxf(phi_out, -1.0f), 319.0f)) + 1;

  // --- wave-uniform bounds (identical in all 8 waves: same 64 rays) --------
  auto wave_min = [](int v) {
#pragma unroll
    for (int off = 32; off > 0; off >>= 1) v = min(v, __shfl_xor(v, off, 64));
    return v;
  };
  auto wave_max = [](int v) {
#pragma unroll
    for (int off = 32; off > 0; off >>= 1) v = max(v, __shfl_xor(v, off, 64));
    return v;
  };
  const int u_lo   = __builtin_amdgcn_readfirstlane(wave_min(i_out_lo));
  const int u_hi   = __builtin_amdgcn_readfirstlane(wave_max(i_out_hi));
  const int fin_lo = __builtin_amdgcn_readfirstlane(wave_max(i_in_lo));
  const int fin_hi = __builtin_amdgcn_readfirstlane(wave_min(i_in_hi));
  const int UL = max(0, u_hi - u_lo);

  // this wave's segment of the block-uniform active interval
  const int seg_lo = u_lo + ((chunk * UL) >> 3);
  const int seg_hi = u_lo + (((chunk + 1) * UL) >> 3);
  // fast sub-range: all lanes interior
  const int f_lo = min(max(seg_lo, fin_lo), seg_hi);
  const int f_hi = min(max(f_lo, fin_hi), seg_hi);

  float acc = 0.0f;   // segment-local composited rgb
  float Tac = 1.0f;   // segment-local transmittance

  // exact (clamped + masked) sample — identical math to the round-1 kernel
  auto masked_sample = [&](int p) {
    const float pf = (float)p;
    const float ix = fmaf(pf, dix, ix0);
    const float iy = fmaf(pf, diy, iy0);
    const float iz = fmaf(pf, diz, iz0);
    if (ix > -1.0f && ix < 256.0f && iy > -1.0f && iy < 256.0f &&
        iz > -1.0f && iz < 256.0f) {
      const float xf = floorf(ix), yf = floorf(iy), zf = floorf(iz);
      const float fx = ix - xf, fy = iy - yf, fz = iz - zf;
      const int x0 = (int)xf, y0 = (int)yf, z0 = (int)zf;
      const float wx0 = (x0 >= 0)   ? 1.0f - fx : 0.0f;
      const float wx1 = (x0 <= 254) ? fx        : 0.0f;
      const float wy0 = (y0 >= 0)   ? 1.0f - fy : 0.0f;
      const float wy1 = (y0 <= 254) ? fy        : 0.0f;
      const float wz0 = (z0 >= 0)   ? 1.0f - fz : 0.0f;
      const float wz1 = (z0 <= 254) ? fz        : 0.0f;
      const int xc0 = max(x0, 0),     xc1 = min(x0 + 1, 255);
      const int yc0 = max(y0, 0),     yc1 = min(y0 + 1, 255);
      const int zc0 = max(z0, 0),     zc1 = min(z0 + 1, 255);
      const int b00 = (zc0 * 256 + yc0) * 256;
      const int b01 = (zc0 * 256 + yc1) * 256;
      const int b10 = (zc1 * 256 + yc0) * 256;
      const int b11 = (zc1 * 256 + yc1) * 256;
      const float v000 = vol[b00 + xc0], v001 = vol[b00 + xc1];
      const float v010 = vol[b01 + xc0], v011 = vol[b01 + xc1];
      const float v100 = vol[b10 + xc0], v101 = vol[b10 + xc1];
      const float v110 = vol[b11 + xc0], v111 = vol[b11 + xc1];
      const float fs =
          wz0 * (wy0 * (wx0 * v000 + wx1 * v001) +
                 wy1 * (wx0 * v010 + wx1 * v011)) +
          wz1 * (wy0 * (wx0 * v100 + wx1 * v101) +
                 wy1 * (wx0 * v110 + wx1 * v111));
      const float wsum  = (wx0 + wx1) * (wy0 + wy1) * (wz0 + wz1);
      const float sigma = DENSITY_C * wsum;
      acc = fmaf(sigma * Tac, fs, acc);
      Tac *= (1.0f + 1e-10f - sigma);
    } else {
      Tac *= (1.0f + 1e-10f);
    }
  };

  // interior trilinear sample: 4 paired 8B loads, no clamps/masks
  auto fast_sample = [&](int p) -> float {
    const float pf = (float)p;
    const float ix = fmaf(pf, dix, ix0);
    const float iy = fmaf(pf, diy, iy0);
    const float iz = fmaf(pf, diz, iz0);
    const int x0 = (int)ix, y0 = (int)iy, z0 = (int)iz;  // >=0: trunc==floor
    const float fx = ix - (float)x0;
    const float fy = iy - (float)y0;
    const float fz = iz - (float)z0;
    const int base = (z0 << 16) + (y0 << 8) + x0;
    const f2a v00 = *(const f2a*)(vol + base);
    const f2a v01 = *(const f2a*)(vol + base + 256);
    const f2a v10 = *(const f2a*)(vol + base + 65536);
    const f2a v11 = *(const f2a*)(vol + base + 65792);
    const float c00 = fmaf(fx, v00.y - v00.x, v00.x);
    const float c01 = fmaf(fx, v01.y - v01.x, v01.x);
    const float c10 = fmaf(fx, v10.y - v10.x, v10.x);
    const float c11 = fmaf(fx, v11.y - v11.x, v11.x);
    const float c0  = fmaf(fy, c01 - c00, c00);
    const float c1  = fmaf(fy, c11 - c10, c10);
    return fmaf(fz, c1 - c0, c0);
  };

  for (int p = seg_lo; p < f_lo; ++p) masked_sample(p);

  int p = f_lo;
#pragma unroll 1
  for (; p + 4 <= f_hi; p += 4) {
    const float fs0 = fast_sample(p);
    const float fs1 = fast_sample(p + 1);
    const float fs2 = fast_sample(p + 2);
    const float fs3 = fast_sample(p + 3);
    const float g = fmaf(0.729f, fs3,
                    fmaf(0.81f,  fs2,
                    fmaf(0.9f,   fs1, fs0)));
    acc = fmaf(Tac * DENSITY_C, g, acc);
    Tac *= 0.6561f;   // 0.9^4
  }
  for (; p < f_hi; ++p) {
    const float fs = fast_sample(p);
    acc = fmaf(Tac * DENSITY_C, fs, acc);
    Tac *= (1.0f - DENSITY_C);
  }

  for (p = f_hi; p < seg_hi; ++p) masked_sample(p);

  __shared__ float lrgb[NCHUNK][PIX_PER_BLOCK];
  __shared__ float lT[NCHUNK][PIX_PER_BLOCK];
  lrgb[chunk][lane] = acc;
  lT[chunk][lane]   = Tac;
  __syncthreads();

  if (threadIdx.x < 64) {
    float a = 0.0f, Tp = 1.0f;
#pragma unroll
    for (int c = 0; c < NCHUNK; ++c) {
      a  = fmaf(Tp, lrgb[c][lane], a);
      Tp *= lT[c][lane];
    }
    raw[pixel] = a;

    float s = a, q = a * a, mn = a, mx = a;
#pragma unroll
    for (int off = 32; off > 0; off >>= 1) {
      s += __shfl_down(s, off, 64);
      q += __shfl_down(q, off, 64);
      mn = fminf(mn, __shfl_down(mn, off, 64));
      mx = fmaxf(mx, __shfl_down(mx, off, 64));
    }
    if (lane == 0) {
      bsum[blockIdx.x]   = s;
      bsumsq[blockIdx.x] = q;
      bmin[blockIdx.x]   = mn;
      bmax[blockIdx.x]   = mx;
    }
  }
}

// ---------------------------------------------------------------------------
// Kernel 2: fused stats + normalize + transpose. 256 blocks x 256 threads;
// stats via per-wave double shuffle reduction (4 waves) + tiny LDS combine.
// ---------------------------------------------------------------------------
__global__ __launch_bounds__(256)
void finalize_kernel(const float* __restrict__ raw,
                     const float* __restrict__ bsum,
                     const float* __restrict__ bsumsq,
                     const float* __restrict__ bmin,
                     const float* __restrict__ bmax,
                     float* __restrict__ out) {
  __shared__ double wS[4], wQ[4];
  __shared__ float wMn[4], wMx[4];
  const int t = threadIdx.x;
  const int lane = t & 63, wv = t >> 6;

  double s = 0.0, q = 0.0;
  float mn = 3.4e38f, mx = -3.4e38f;
#pragma unroll
  for (int i = 0; i < 4; ++i) {
    const int idx = t + i * 256;
    s += (double)bsum[idx];
    q += (double)bsumsq[idx];
    mn = fminf(mn, bmin[idx]);
    mx = fmaxf(mx, bmax[idx]);
  }
#pragma unroll
  for (int off = 32; off > 0; off >>= 1) {
    s += __shfl_down(s, off, 64);
    q += __shfl_down(q, off, 64);
    mn = fminf(mn, __shfl_down(mn, off, 64));
    mx = fmaxf(mx, __shfl_down(mx, off, 64));
  }
  if (lane == 0) { wS[wv] = s; wQ[wv] = q; wMn[wv] = mn; wMx[wv] = mx; }
  __syncthreads();
  const double sum   = wS[0] + wS[1] + wS[2] + wS[3];
  const double sumsq = wQ[0] + wQ[1] + wQ[2] + wQ[3];
  const float  gmn = fminf(fminf(wMn[0], wMn[1]), fminf(wMn[2], wMn[3]));
  const float  gmx = fmaxf(fmaxf(wMx[0], wMx[1]), fmaxf(wMx[2], wMx[3]));

  const double N = 65536.0;
  const double mean = sum / N;
  double var = (sumsq - sum * sum / N) / (N - 1.0);
  if (var < 0.0) var = 0.0;
  const float stdeps = (float)sqrt(var) + 1e-8f;
  const float inv_std = 1.0f / stdeps;
  const float fmean = (float)mean;
  const float smin = (gmn - fmean) * inv_std;
  const float smax = (gmx - fmean) * inv_std;
  const float inv_range = 1.0f / (smax - smin + 1e-8f);

  const int o = blockIdx.x * 256 + t;
  const int wq = o >> 8;    // output row (W index)
  const int hq = o & 255;   // output col (H index)
  const float sv = (raw[hq * 256 + wq] - fmean) * inv_std;
  out[o] = (sv - smin + 1e-8f) * inv_range;
}

extern "C" void kernel_launch(void* const* d_in, const int* in_sizes, int n_in,
                              void* d_out, int out_size, void* d_ws, size_t ws_size,
                              hipStream_t stream) {
  const float* vol = (const float*)d_in[0];  // (256,256,256) fp32
  const float* R   = (const float*)d_in[1];  // (1,3,3)
  const float* T   = (const float*)d_in[2];  // (1,3)
  float* out = (float*)d_out;                // 65536 fp32

  float* raw    = (float*)d_ws;              // 65536
  float* bsum   = raw + 65536;               // 1024
  float* bsumsq = bsum + 1024;               // 1024
  float* bmin   = bsumsq + 1024;             // 1024
  float* bmax   = bmin + 1024;               // 1024

  render_kernel<<<1024, 512, 0, stream>>>(vol, R, T, raw, bsum, bsumsq, bmin, bmax);
  finalize_kernel<<<256, 256, 0, stream>>>(raw, bsum, bsumsq, bmin, bmax, out);
}

// Round 6
// 121.493 us; speedup vs baseline: 1.4098x; 1.0327x over previous
//
#include <hip/hip_runtime.h>

#define NPTS 320
#define NCHUNK 8
#define D0 2.0f
#define DSTEP (4.0f / 319.0f)
#define HALFV (765.0f / 512.0f)  // (3/256)*255*0.5
#define DENSITY_C 0.1f

// 8-byte vector load with only 4-byte guaranteed alignment (x0 is arbitrary).
typedef float f2a __attribute__((ext_vector_type(2), aligned(4)));

// ---------------------------------------------------------------------------
// Kernel 1: ray-march. Block = 512 threads = 8 waves over the SAME 64 rays.
// Wave pixel footprint is a 32(w) x 2(h) TILE (round-6 change): x-span per
// voxel row drops 260B->~44-132B and the two pixel rows share voxel rows, so
// line-requests/sample fall ~2x (R2-R5 showed time tracks line-requests, not
// vmem instruction count). Block-uniform active interval (wave-reduced union
// of per-ray slab intervals) split evenly across the 8 waves; lanes walk p in
// lockstep (R4 lesson). Fast path (paired 8B loads, regrouped t=0.9
// recurrence) only where ALL lanes are interior. Segmented compositing via LDS.
// ---------------------------------------------------------------------------
__global__ __launch_bounds__(512, 8)
void render_kernel(const float* __restrict__ vol,
                   const float* __restrict__ R,
                   const float* __restrict__ T,
                   float* __restrict__ raw,
                   float* __restrict__ bsum,
                   float* __restrict__ bsumsq,
                   float* __restrict__ bmin,
                   float* __restrict__ bmax) {
  const int lane  = threadIdx.x & 63;
  const int chunk = threadIdx.x >> 6;
  // 32x2 tile: block b covers w in [ (b&7)*32, +32 ), h in [ (b>>3)*2, +2 )
  const int w = ((blockIdx.x & 7) << 5) + (lane & 31);
  const int h = ((blockIdx.x >> 3) << 1) + (lane >> 5);

  // camera-plane coords / FOCAL(=2)
  const float xh = (w * (2.0f / 255.0f) - 1.0f) * 0.5f;
  const float yh = (h * (2.0f / 255.0f) - 1.0f) * 0.5f;

  const float R00 = R[0], R01 = R[1], R02 = R[2];
  const float R10 = R[3], R11 = R[4], R12 = R[5];
  const float R20 = R[6], R21 = R[7], R22 = R[8];
  const float T0 = T[0], T1 = T[1], T2 = T[2];

  // pw = R * (pcam - T); pcam = (xh*d, yh*d, d) -> voxel coords LINEAR in d.
  const float S = 127.5f / HALFV;
  const float Cx = R00 * xh + R01 * yh + R02;
  const float Cy = R10 * xh + R11 * yh + R12;
  const float Cz = R20 * xh + R21 * yh + R22;
  const float Kx = -(R00 * T0 + R01 * T1 + R02 * T2);
  const float Ky = -(R10 * T0 + R11 * T1 + R12 * T2);
  const float Kz = -(R20 * T0 + R21 * T1 + R22 * T2);
  const float ax = Cx * S, bx = Kx * S + 127.5f;
  const float ay = Cy * S, by = Ky * S + 127.5f;
  const float az = Cz * S, bz = Kz * S + 127.5f;
  // ix(p) = ix0 + p*dix with d = D0 + p*DSTEP
  const float ix0 = ax * D0 + bx, dix = ax * DSTEP;
  const float iy0 = ay * D0 + by, diy = ay * DSTEP;
  const float iz0 = az * D0 + bz, diz = az * DSTEP;

  // --- per-ray slab intervals in p-space -----------------------------------
  float plo_in = -1e9f, phi_in = 1e9f, plo_out = -1e9f, phi_out = 1e9f;
  auto slab = [](float a, float b, float L, float H, float& lo, float& hi) {
    if (fabsf(a) < 1e-5f) {           // drift over 320 steps < 0.0032 < margin
      if (b < L || b > H) { lo = 1e9f; hi = -1e9f; }
    } else {
      const float p1 = (L - b) / a, p2 = (H - b) / a;
      lo = fmaxf(lo, fminf(p1, p2));
      hi = fminf(hi, fmaxf(p1, p2));
    }
  };
  slab(dix, ix0, 0.01f, 254.99f, plo_in, phi_in);
  slab(diy, iy0, 0.01f, 254.99f, plo_in, phi_in);
  slab(diz, iz0, 0.01f, 254.99f, plo_in, phi_in);
  slab(dix, ix0, -1.01f, 256.01f, plo_out, phi_out);
  slab(diy, iy0, -1.01f, 256.01f, plo_out, phi_out);
  slab(diz, iz0, -1.01f, 256.01f, plo_out, phi_out);

  const int i_in_lo  = (int)ceilf(fminf(fmaxf(plo_in, 0.0f), 320.0f));
  const int i_in_hi  = (int)floorf(fminf(fmaxf(phi_in, -1.0f), 319.0f)) + 1;
  const int i_out_lo = (int)ceilf(fminf(fmaxf(plo_out, 0.0f), 320.0f));
  const int i_out_hi = (int)floorf(fminf(fmaxf(phi_out, -1.0f), 319.0f)) + 1;

  // --- wave-uniform bounds (identical in all 8 waves: same 64 rays) --------
  auto wave_min = [](int v) {
#pragma unroll
    for (int off = 32; off > 0; off >>= 1) v = min(v, __shfl_xor(v, off, 64));
    return v;
  };
  auto wave_max = [](int v) {
#pragma unroll
    for (int off = 32; off > 0; off >>= 1) v = max(v, __shfl_xor(v, off, 64));
    return v;
  };
  const int u_lo   = __builtin_amdgcn_readfirstlane(wave_min(i_out_lo));
  const int u_hi   = __builtin_amdgcn_readfirstlane(wave_max(i_out_hi));
  const int fin_lo = __builtin_amdgcn_readfirstlane(wave_max(i_in_lo));
  const int fin_hi = __builtin_amdgcn_readfirstlane(wave_min(i_in_hi));
  const int UL = max(0, u_hi - u_lo);

  // this wave's segment of the block-uniform active interval
  const int seg_lo = u_lo + ((chunk * UL) >> 3);
  const int seg_hi = u_lo + (((chunk + 1) * UL) >> 3);
  // fast sub-range: all lanes interior
  const int f_lo = min(max(seg_lo, fin_lo), seg_hi);
  const int f_hi = min(max(f_lo, fin_hi), seg_hi);

  float acc = 0.0f;   // segment-local composited rgb
  float Tac = 1.0f;   // segment-local transmittance

  // exact (clamped + masked) sample — identical math to the round-1 kernel
  auto masked_sample = [&](int p) {
    const float pf = (float)p;
    const float ix = fmaf(pf, dix, ix0);
    const float iy = fmaf(pf, diy, iy0);
    const float iz = fmaf(pf, diz, iz0);
    if (ix > -1.0f && ix < 256.0f && iy > -1.0f && iy < 256.0f &&
        iz > -1.0f && iz < 256.0f) {
      const float xf = floorf(ix), yf = floorf(iy), zf = floorf(iz);
      const float fx = ix - xf, fy = iy - yf, fz = iz - zf;
      const int x0 = (int)xf, y0 = (int)yf, z0 = (int)zf;
      const float wx0 = (x0 >= 0)   ? 1.0f - fx : 0.0f;
      const float wx1 = (x0 <= 254) ? fx        : 0.0f;
      const float wy0 = (y0 >= 0)   ? 1.0f - fy : 0.0f;
      const float wy1 = (y0 <= 254) ? fy        : 0.0f;
      const float wz0 = (z0 >= 0)   ? 1.0f - fz : 0.0f;
      const float wz1 = (z0 <= 254) ? fz        : 0.0f;
      const int xc0 = max(x0, 0),     xc1 = min(x0 + 1, 255);
      const int yc0 = max(y0, 0),     yc1 = min(y0 + 1, 255);
      const int zc0 = max(z0, 0),     zc1 = min(z0 + 1, 255);
      const int b00 = (zc0 * 256 + yc0) * 256;
      const int b01 = (zc0 * 256 + yc1) * 256;
      const int b10 = (zc1 * 256 + yc0) * 256;
      const int b11 = (zc1 * 256 + yc1) * 256;
      const float v000 = vol[b00 + xc0], v001 = vol[b00 + xc1];
      const float v010 = vol[b01 + xc0], v011 = vol[b01 + xc1];
      const float v100 = vol[b10 + xc0], v101 = vol[b10 + xc1];
      const float v110 = vol[b11 + xc0], v111 = vol[b11 + xc1];
      const float fs =
          wz0 * (wy0 * (wx0 * v000 + wx1 * v001) +
                 wy1 * (wx0 * v010 + wx1 * v011)) +
          wz1 * (wy0 * (wx0 * v100 + wx1 * v101) +
                 wy1 * (wx0 * v110 + wx1 * v111));
      const float wsum  = (wx0 + wx1) * (wy0 + wy1) * (wz0 + wz1);
      const float sigma = DENSITY_C * wsum;
      acc = fmaf(sigma * Tac, fs, acc);
      Tac *= (1.0f + 1e-10f - sigma);
    } else {
      Tac *= (1.0f + 1e-10f);
    }
  };

  // interior trilinear sample: 4 paired 8B loads, no clamps/masks
  auto fast_sample = [&](int p) -> float {
    const float pf = (float)p;
    const float ix = fmaf(pf, dix, ix0);
    const float iy = fmaf(pf, diy, iy0);
    const float iz = fmaf(pf, diz, iz0);
    const int x0 = (int)ix, y0 = (int)iy, z0 = (int)iz;  // >=0: trunc==floor
    const float fx = ix - (float)x0;
    const float fy = iy - (float)y0;
    const float fz = iz - (float)z0;
    const int base = (z0 << 16) + (y0 << 8) + x0;
    const f2a v00 = *(const f2a*)(vol + base);
    const f2a v01 = *(const f2a*)(vol + base + 256);
    const f2a v10 = *(const f2a*)(vol + base + 65536);
    const f2a v11 = *(const f2a*)(vol + base + 65792);
    const float c00 = fmaf(fx, v00.y - v00.x, v00.x);
    const float c01 = fmaf(fx, v01.y - v01.x, v01.x);
    const float c10 = fmaf(fx, v10.y - v10.x, v10.x);
    const float c11 = fmaf(fx, v11.y - v11.x, v11.x);
    const float c0  = fmaf(fy, c01 - c00, c00);
    const float c1  = fmaf(fy, c11 - c10, c10);
    return fmaf(fz, c1 - c0, c0);
  };

  for (int p = seg_lo; p < f_lo; ++p) masked_sample(p);

  int p = f_lo;
#pragma unroll 2
  for (; p + 4 <= f_hi; p += 4) {
    const float fs0 = fast_sample(p);
    const float fs1 = fast_sample(p + 1);
    const float fs2 = fast_sample(p + 2);
    const float fs3 = fast_sample(p + 3);
    const float g = fmaf(0.729f, fs3,
                    fmaf(0.81f,  fs2,
                    fmaf(0.9f,   fs1, fs0)));
    acc = fmaf(Tac * DENSITY_C, g, acc);
    Tac *= 0.6561f;   // 0.9^4
  }
  for (; p < f_hi; ++p) {
    const float fs = fast_sample(p);
    acc = fmaf(Tac * DENSITY_C, fs, acc);
    Tac *= (1.0f - DENSITY_C);
  }

  for (p = f_hi; p < seg_hi; ++p) masked_sample(p);

  __shared__ float lrgb[NCHUNK][64];
  __shared__ float lT[NCHUNK][64];
  lrgb[chunk][lane] = acc;
  lT[chunk][lane]   = Tac;
  __syncthreads();

  if (threadIdx.x < 64) {
    float a = 0.0f, Tp = 1.0f;
#pragma unroll
    for (int c = 0; c < NCHUNK; ++c) {
      a  = fmaf(Tp, lrgb[c][lane], a);
      Tp *= lT[c][lane];
    }
    raw[h * 256 + w] = a;

    float s = a, q = a * a, mn = a, mx = a;
#pragma unroll
    for (int off = 32; off > 0; off >>= 1) {
      s += __shfl_down(s, off, 64);
      q += __shfl_down(q, off, 64);
      mn = fminf(mn, __shfl_down(mn, off, 64));
      mx = fmaxf(mx, __shfl_down(mx, off, 64));
    }
    if (lane == 0) {
      bsum[blockIdx.x]   = s;
      bsumsq[blockIdx.x] = q;
      bmin[blockIdx.x]   = mn;
      bmax[blockIdx.x]   = mx;
    }
  }
}

// ---------------------------------------------------------------------------
// Kernel 2: fused stats + normalize + transpose. 256 blocks x 256 threads;
// stats via per-wave double shuffle reduction (4 waves) + tiny LDS combine.
// ---------------------------------------------------------------------------
__global__ __launch_bounds__(256)
void finalize_kernel(const float* __restrict__ raw,
                     const float* __restrict__ bsum,
                     const float* __restrict__ bsumsq,
                     const float* __restrict__ bmin,
                     const float* __restrict__ bmax,
                     float* __restrict__ out) {
  __shared__ double wS[4], wQ[4];
  __shared__ float wMn[4], wMx[4];
  const int t = threadIdx.x;
  const int lane = t & 63, wv = t >> 6;

  double s = 0.0, q = 0.0;
  float mn = 3.4e38f, mx = -3.4e38f;
#pragma unroll
  for (int i = 0; i < 4; ++i) {
    const int idx = t + i * 256;
    s += (double)bsum[idx];
    q += (double)bsumsq[idx];
    mn = fminf(mn, bmin[idx]);
    mx = fmaxf(mx, bmax[idx]);
  }
#pragma unroll
  for (int off = 32; off > 0; off >>= 1) {
    s += __shfl_down(s, off, 64);
    q += __shfl_down(q, off, 64);
    mn = fminf(mn, __shfl_down(mn, off, 64));
    mx = fmaxf(mx, __shfl_down(mx, off, 64));
  }
  if (lane == 0) { wS[wv] = s; wQ[wv] = q; wMn[wv] = mn; wMx[wv] = mx; }
  __syncthreads();
  const double sum   = wS[0] + wS[1] + wS[2] + wS[3];
  const double sumsq = wQ[0] + wQ[1] + wQ[2] + wQ[3];
  const float  gmn = fminf(fminf(wMn[0], wMn[1]), fminf(wMn[2], wMn[3]));
  const float  gmx = fmaxf(fmaxf(wMx[0], wMx[1]), fmaxf(wMx[2], wMx[3]));

  const double N = 65536.0;
  const double mean = sum / N;
  double var = (sumsq - sum * sum / N) / (N - 1.0);
  if (var < 0.0) var = 0.0;
  const float stdeps = (float)sqrt(var) + 1e-8f;
  const float inv_std = 1.0f / stdeps;
  const float fmean = (float)mean;
  const float smin = (gmn - fmean) * inv_std;
  const float smax = (gmx - fmean) * inv_std;
  const float inv_range = 1.0f / (smax - smin + 1e-8f);

  const int o = blockIdx.x * 256 + t;
  const int wq = o >> 8;    // output row (W index)
  const int hq = o & 255;   // output col (H index)
  const float sv = (raw[hq * 256 + wq] - fmean) * inv_std;
  out[o] = (sv - smin + 1e-8f) * inv_range;
}

extern "C" void kernel_launch(void* const* d_in, const int* in_sizes, int n_in,
                              void* d_out, int out_size, void* d_ws, size_t ws_size,
                              hipStream_t stream) {
  const float* vol = (const float*)d_in[0];  // (256,256,256) fp32
  const float* R   = (const float*)d_in[1];  // (1,3,3)
  const float* T   = (const float*)d_in[2];  // (1,3)
  float* out = (float*)d_out;                // 65536 fp32

  float* raw    = (float*)d_ws;              // 65536
  float* bsum   = raw + 65536;               // 1024
  float* bsumsq = bsum + 1024;               // 1024
  float* bmin   = bsumsq + 1024;             // 1024
  float* bmax   = bmin + 1024;               // 1024

  render_kernel<<<1024, 512, 0, stream>>>(vol, R, T, raw, bsum, bsumsq, bmin, bmax);
  finalize_kernel<<<256, 256, 0, stream>>>(raw, bsum, bsumsq, bmin, bmax, out);
}